// Round 18
// baseline (88.066 us; speedup 1.0000x reference)
//
#include <hip/hip_runtime.h>
#include <hip/hip_bf16.h>
#include <stdint.h>

typedef unsigned short ushortT;
typedef float f32x4 __attribute__((ext_vector_type(4)));
typedef float f32x2 __attribute__((ext_vector_type(2)));
typedef unsigned u32x4 __attribute__((ext_vector_type(4)));
typedef ushortT u16x4 __attribute__((ext_vector_type(4)));
typedef ushortT u16x8 __attribute__((ext_vector_type(8)));

#define MM 1024
#define NN 4096
#define DD 128
#define EPSX 0.05f
#define STRENGTH 0.5f
#define TINYX 1e-12f
#define NITER 50
#define MIN_IT 2
#define REL_EPS 5e-2f

// ---- ws layout (float indices) ----
#define WS_MAXCAP  1
#define WS_KSUM_SLOTS 16   // 64 slots
#define WS_SCORE_SLOTS 80  // 64 slots (fallback)
#define WS_T_SLOTS 144     // 2 x 64 slots (fallback)
#define WS_U 512           // fallback u
#define WS_V 1536          // fallback v
#define WS_CMAX 512        // 512 per-WG cost-max slots (512..1023, fast path)
#define K_BYTE_OFF 32768
#define FAST_NEED (32768ull + 2ull * 8388608ull)

// ---- fast-path layout ----
#define WSN_U   1024       // 1024 floats
#define WSN_V   2048       // 4096 floats
#define WSN_T   6144       // 2 x 256 per-WG t slots
#define WSB_FLAGS 6912     // 512 u32 arrival flags (6912..7423)
#define WSB_MST 7424       // master release word
#define WSN_R   7680       // 2 x 256 per-WG rel slots
#define NWG 256
#define NTHR 512

__device__ inline float bfl(unsigned u) { return __uint_as_float(u << 16); }
__device__ inline float bfh(unsigned u) { return __uint_as_float(u & 0xffff0000u); }
__device__ inline float bf2f(ushortT u) { return __uint_as_float(((unsigned)u) << 16); }
__device__ inline ushortT f2bf(float f) {
    unsigned b = __float_as_uint(f);
    b += 0x7fffu + ((b >> 16) & 1u);
    return (ushortT)(b >> 16);
}
__device__ inline float wave_sum(float v) {
    for (int o = 32; o; o >>= 1) v += __shfl_down(v, o);
    return v;
}
__device__ inline float wave_max(float v) {
    for (int o = 32; o; o >>= 1) v = fmaxf(v, __shfl_down(v, o));
    return v;
}

__device__ inline void g_store(float* p, float v) {
    __hip_atomic_store(p, v, __ATOMIC_RELAXED, __HIP_MEMORY_SCOPE_AGENT);
}
__device__ inline float g_load(const float* p) {
    return __hip_atomic_load((float*)p, __ATOMIC_RELAXED, __HIP_MEMORY_SCOPE_AGENT);
}
__device__ inline void g_store_u(unsigned* p, unsigned v) {
    __hip_atomic_store(p, v, __ATOMIC_RELAXED, __HIP_MEMORY_SCOPE_AGENT);
}
__device__ inline unsigned g_load_u(const unsigned* p) {
    return __hip_atomic_load((unsigned*)p, __ATOMIC_RELAXED, __HIP_MEMORY_SCOPE_AGENT);
}
__device__ inline f32x4 load4_sc1(const float* p) {
    f32x4 x;
    asm volatile("global_load_dwordx4 %0, %1, off sc1\n\ts_waitcnt vmcnt(0)"
                 : "=&v"(x) : "v"(p) : "memory");
    return x;
}

__device__ inline void stage_v8(const float* vbase, int t, float* lv) {
    f32x4 x0, x1;
    const float* p0 = vbase + (t << 3);
    const float* p1 = p0 + 4;
    asm volatile(
        "global_load_dwordx4 %0, %2, off sc1\n\t"
        "global_load_dwordx4 %1, %3, off sc1\n\t"
        "s_waitcnt vmcnt(0)"
        : "=&v"(x0), "=&v"(x1) : "v"(p0), "v"(p1) : "memory");
    *(f32x4*)&lv[t << 3] = x0;
    *(f32x4*)&lv[(t << 3) + 4] = x1;
}
__device__ inline void stage_u2(const float* ubase, int t, float* lu) {
    f32x2 x0;
    const float* p0 = ubase + (t << 1);
    asm volatile(
        "global_load_dwordx2 %0, %1, off sc1\n\t"
        "s_waitcnt vmcnt(0)"
        : "=&v"(x0) : "v"(p0) : "memory");
    *(f32x2*)&lu[t << 1] = x0;
}

// Zero-contention flag grid barrier for the 256-WG loop (monotonic rounds).
__device__ inline void grid_bar(unsigned* w, unsigned round) {
    asm volatile("s_waitcnt vmcnt(0)" ::: "memory");
    __syncthreads();
    if (blockIdx.x == 0) {
        if (threadIdx.x < 64) {
            if (threadIdx.x == 0) g_store_u(&w[WSB_FLAGS], round);
            const unsigned* fp = &w[WSB_FLAGS + (threadIdx.x << 2)];
            for (;;) {
                u32x4 f;
                asm volatile("global_load_dwordx4 %0, %1, off sc1\n\ts_waitcnt vmcnt(0)"
                             : "=&v"(f) : "v"(fp) : "memory");
                unsigned mn = f.x < f.y ? f.x : f.y;
                unsigned mz = f.z < f.w ? f.z : f.w;
                mn = mn < mz ? mn : mz;
#pragma unroll
                for (int o = 32; o; o >>= 1) {
                    unsigned ot = (unsigned)__shfl_xor((int)mn, o);
                    mn = mn < ot ? mn : ot;
                }
                if (mn >= round) break;
            }
            if (threadIdx.x == 0) g_store_u(&w[WSB_MST], round);
        }
    } else {
        if (threadIdx.x == 0) {
            g_store_u(&w[WSB_FLAGS + blockIdx.x], round);
            while (g_load_u(&w[WSB_MST]) < round) {}
            asm volatile("" ::: "memory");
        }
    }
    __syncthreads();
}

// ---------------- tiny init: scalars/ksum/flags/out accumulators + maxcap ----------------
__global__ void k_zero(float* ws, float* out, const float* cap) {
    int t = threadIdx.x;  // 256
    for (int i = t; i < 512; i += 256) ws[i] = 0.f;          // scalars + ksum slots
    for (int i = 6912 + t; i < 7680; i += 256) ws[i] = 0.f;  // 512 flags + master
    if (t == 0) { out[0] = 0.f; out[1 + (size_t)MM * NN] = 0.f; }
    float m = 0.f;
    for (int j = t; j < NN; j += 256) m = fmaxf(m, cap[j]);
    __shared__ float red[4];
    m = wave_max(m);
    if ((t & 63) == 0) red[t >> 6] = m;
    __syncthreads();
    if (t == 0) ws[WS_MAXCAP] = fmaxf(fmaxf(red[0], red[1]), fmaxf(red[2], red[3]));
}

// ====== fused cost+K kernel: 512 WGs x 256 thr (2/CU, co-resident), plain launch ======
// GEMM (64x128 tile, reg dbuf) -> cost in registers -> per-WG max (sc1 slot) ->
// flag barrier (round 1, 512 flags) -> global max -> exp in registers ->
// K (plain stores) + KT via LDS transpose + ksum atomics. Kernel boundary
// flushes K/KT so k_loop's plain loads see them (proven pattern).
__global__ __launch_bounds__(256) void k_costK(const float* __restrict__ U,
                                               const float* __restrict__ V,
                                               const float* __restrict__ b,
                                               float* __restrict__ ws,
                                               ushortT* __restrict__ K,
                                               ushortT* __restrict__ KT) {
    __shared__ __align__(16) char smem[25600];
    float* As = (float*)smem;                 // [32][68]  (8704 B)
    float* Bs = (float*)(smem + 8704);        // [32][132] (16896 B)
    ushortT* tile = (ushortT*)smem;           // [64][136] u16 (17408 B, reuse)
    __shared__ float su2[64], sv2[128];
    __shared__ float red[4];
    __shared__ float shmax;
    int t = threadIdx.x;
    int bid = blockIdx.x;
    unsigned* wsu = (unsigned*)ws;
    int tr0 = (bid >> 5) << 6;   // 16 row tiles (64 rows)
    int tc0 = (bid & 31) << 7;   // 32 col tiles (128 cols)
    int tx = t & 15, ty = t >> 4;
    float acc[4][8] = {};
    float na = 0.f, nb = 0.f;
    float4 pa[2], pb[4];
#pragma unroll
    for (int p = 0; p < 2; p++) {
        int f = t + (p << 8);
        int r = f >> 3, kp = (f & 7) << 2;
        pa[p] = *(const float4*)(U + (size_t)(tr0 + r) * DD + kp);
    }
#pragma unroll
    for (int p = 0; p < 4; p++) {
        int f = t + (p << 8);
        int r = f >> 3, kp = (f & 7) << 2;
        pb[p] = *(const float4*)(V + (size_t)(tc0 + r) * DD + kp);
    }
    for (int kk = 0; kk < DD; kk += 32) {
#pragma unroll
        for (int p = 0; p < 2; p++) {
            int f = t + (p << 8);
            int r = f >> 3, kp = (f & 7) << 2;
            As[kp * 68 + r] = pa[p].x; As[(kp + 1) * 68 + r] = pa[p].y;
            As[(kp + 2) * 68 + r] = pa[p].z; As[(kp + 3) * 68 + r] = pa[p].w;
        }
#pragma unroll
        for (int p = 0; p < 4; p++) {
            int f = t + (p << 8);
            int r = f >> 3, kp = (f & 7) << 2;
            Bs[kp * 132 + r] = pb[p].x; Bs[(kp + 1) * 132 + r] = pb[p].y;
            Bs[(kp + 2) * 132 + r] = pb[p].z; Bs[(kp + 3) * 132 + r] = pb[p].w;
        }
        __syncthreads();
        if (kk + 32 < DD) {
#pragma unroll
            for (int p = 0; p < 2; p++) {
                int f = t + (p << 8);
                int r = f >> 3, kp = (f & 7) << 2;
                pa[p] = *(const float4*)(U + (size_t)(tr0 + r) * DD + kk + 32 + kp);
            }
#pragma unroll
            for (int p = 0; p < 4; p++) {
                int f = t + (p << 8);
                int r = f >> 3, kp = (f & 7) << 2;
                pb[p] = *(const float4*)(V + (size_t)(tc0 + r) * DD + kk + 32 + kp);
            }
        }
        if (t < 64) {
            float s = 0.f;
            for (int k = 0; k < 32; k++) { float x = As[k * 68 + t]; s = fmaf(x, x, s); }
            na += s;
        } else if (t < 192) {
            int c = t - 64;
            float s = 0.f;
            for (int k = 0; k < 32; k++) { float x = Bs[k * 132 + c]; s = fmaf(x, x, s); }
            nb += s;
        }
#pragma unroll 2
        for (int k = 0; k < 32; ++k) {
            f32x4 a0 = *(const f32x4*)&As[k * 68 + (ty << 2)];
            f32x4 b0 = *(const f32x4*)&Bs[k * 132 + (tx << 3)];
            f32x4 b1 = *(const f32x4*)&Bs[k * 132 + (tx << 3) + 4];
            float av[4] = {a0.x, a0.y, a0.z, a0.w};
            float bv[8] = {b0.x, b0.y, b0.z, b0.w, b1.x, b1.y, b1.z, b1.w};
#pragma unroll
            for (int i = 0; i < 4; i++)
#pragma unroll
                for (int j = 0; j < 8; j++)
                    acc[i][j] = fmaf(av[i], bv[j], acc[i][j]);
        }
        __syncthreads();
    }
    if (t < 64) su2[t] = na;
    else if (t < 192) sv2[t - 64] = nb;
    __syncthreads();
    float u2l[4], v2l[8];
#pragma unroll
    for (int i = 0; i < 4; i++) u2l[i] = su2[(ty << 2) + i];
#pragma unroll
    for (int j = 0; j < 8; j++) v2l[j] = sv2[(tx << 3) + j];
    float lmax = 0.f;
#pragma unroll
    for (int i = 0; i < 4; i++)
#pragma unroll
        for (int j = 0; j < 8; j++) {
            float c = fmaxf(u2l[i] + v2l[j] - 2.f * acc[i][j], 0.f);
            acc[i][j] = c;                       // acc now holds raw cost
            lmax = fmaxf(lmax, c);
        }
    lmax = wave_max(lmax);
    if ((t & 63) == 0) red[t >> 6] = lmax;
    __syncthreads();
    if (t == 0) {
        float m = fmaxf(fmaxf(red[0], red[1]), fmaxf(red[2], red[3]));
        g_store(ws + WS_CMAX + bid, m);
    }

    // ---- 512-WG flag barrier, round 1 ----
    {
        asm volatile("s_waitcnt vmcnt(0)" ::: "memory");
        __syncthreads();
        if (bid == 0) {
            if (t < 64) {
                if (t == 0) g_store_u(&wsu[WSB_FLAGS], 1u);
                const unsigned* fp0 = &wsu[WSB_FLAGS + (t << 3)];
                for (;;) {
                    u32x4 f0, f1;
                    asm volatile(
                        "global_load_dwordx4 %0, %2, off sc1\n\t"
                        "global_load_dwordx4 %1, %3, off sc1\n\t"
                        "s_waitcnt vmcnt(0)"
                        : "=&v"(f0), "=&v"(f1) : "v"(fp0), "v"(fp0 + 4) : "memory");
                    unsigned mn = f0.x < f0.y ? f0.x : f0.y;
                    unsigned m2 = f0.z < f0.w ? f0.z : f0.w;
                    unsigned m3 = f1.x < f1.y ? f1.x : f1.y;
                    unsigned m4 = f1.z < f1.w ? f1.z : f1.w;
                    mn = mn < m2 ? mn : m2; m3 = m3 < m4 ? m3 : m4;
                    mn = mn < m3 ? mn : m3;
#pragma unroll
                    for (int o = 32; o; o >>= 1) {
                        unsigned ot = (unsigned)__shfl_xor((int)mn, o);
                        mn = mn < ot ? mn : ot;
                    }
                    if (mn >= 1u) break;
                }
                if (t == 0) g_store_u(&wsu[WSB_MST], 1u);
            }
        } else {
            if (t == 0) {
                g_store_u(&wsu[WSB_FLAGS + bid], 1u);
                while (g_load_u(&wsu[WSB_MST]) < 1u) {}
                asm volatile("" ::: "memory");
            }
        }
        __syncthreads();
    }

    // ---- global max (wave 0: 512 slots = 8/lane) ----
    if (t < 64) {
        f32x4 m0 = load4_sc1(ws + WS_CMAX + (t << 3));
        f32x4 m1 = load4_sc1(ws + WS_CMAX + (t << 3) + 4);
        float m = fmaxf(fmaxf(fmaxf(m0.x, m0.y), fmaxf(m0.z, m0.w)),
                        fmaxf(fmaxf(m1.x, m1.y), fmaxf(m1.z, m1.w)));
#pragma unroll
        for (int o = 32; o; o >>= 1) m = fmaxf(m, __shfl_xor(m, o));
        if (t == 0) shmax = m;
    }
    __syncthreads();
    float inv_mc = 1.f / (shmax + TINYX);
    float inv_cap = 1.f / (ws[WS_MAXCAP] + TINYX);
    f32x4 cap0 = *(const f32x4*)&b[tc0 + (tx << 3)];
    f32x4 cap1 = *(const f32x4*)&b[tc0 + (tx << 3) + 4];
    float pen[8];
#pragma unroll
    for (int j = 0; j < 8; j++) {
        float cj = (j < 4) ? cap0[j] : cap1[j - 4];
        pen[j] = STRENGTH * (1.f - cj * inv_cap);
    }
    float lsum = 0.f;
#pragma unroll
    for (int i = 0; i < 4; i++) {
        u16x8 kb;
#pragma unroll
        for (int j = 0; j < 8; j++) {
            float c = acc[i][j] * inv_mc + pen[j];
            float kf = expf(-c * (1.f / EPSX));
            lsum += kf;
            kb[j] = f2bf(kf);
        }
        *(u16x8*)&K[(size_t)(tr0 + (ty << 2) + i) * NN + tc0 + (tx << 3)] = kb;
        *(u16x8*)&tile[((ty << 2) + i) * 136 + (tx << 3)] = kb;
    }
    __syncthreads();
    // transpose: thread t -> col c = t>>1 (0..127), half h = t&1 (rows h*32..+31)
    {
        int c = t >> 1, h = t & 1;
        ushortT* dst = &KT[(size_t)(tc0 + c) * MM + tr0 + (h << 5)];
#pragma unroll
        for (int q = 0; q < 4; ++q) {
            u16x8 kb;
#pragma unroll
            for (int e = 0; e < 8; ++e) kb[e] = tile[((h << 5) + (q << 3) + e) * 136 + c];
            *(u16x8*)(dst + (q << 3)) = kb;
        }
    }
    lsum = wave_sum(lsum);
    if ((t & 63) == 0) red[t >> 6] = lsum;
    __syncthreads();
    if (t == 0)
        atomicAdd(&ws[WS_KSUM_SLOTS + (bid & 63)], red[0] + red[1] + red[2] + red[3]);
}

// ============ persistent loop kernel (PLAIN launch; 256 WGs co-resident) ============
// barcnt starts at 1: k_costK consumed barrier round 1 (flags[0..255] = 1, master = 1).
__global__ __launch_bounds__(NTHR, 1) void k_loop(const ushortT* __restrict__ K,
                                                  const ushortT* __restrict__ KT,
                                                  const float* __restrict__ a,
                                                  const float* __restrict__ b,
                                                  const float* __restrict__ mbp,
                                                  float* __restrict__ wsf,
                                                  float* __restrict__ out) {
    __shared__ __align__(16) float lv[4096];
    __shared__ __align__(16) float lu[1024];
    __shared__ float red[8];
    __shared__ float cws[16];
    __shared__ float cwr[8];
    __shared__ float relu4[4];
    __shared__ float lu4s[4];
    __shared__ float gsh;
    __shared__ float rsh;
    __shared__ float sh0;

    int t = threadIdx.x, lane = t & 63, wid = t >> 6;
    int bid = blockIdx.x;
    unsigned* wsu = (unsigned*)wsf;
    float mb = mbp[0];
    float* plan = out + 1;
    float* usage = out + 2 + (size_t)MM * NN;
    int r0 = bid << 2;
    int j0 = (bid << 4) + (wid << 1);
    unsigned barcnt = 1;

    float a_reg = (t < 4) ? a[r0 + t] : 0.f;
    float b_reg0 = 0.f, b_reg1 = 0.f;
    if (lane == 0) { b_reg0 = b[j0]; b_reg1 = b[j0 + 1]; }
    float v_reg0 = 1.f, v_reg1 = 1.f;

    // ---- phase 0 (local only, no barrier): u = mb/Ksum ----
    if (wid == 0) {
        float s = g_load(wsf + WS_KSUM_SLOTS + lane);
        s = wave_sum(s);
        if (lane == 0) sh0 = mb / (s + TINYX);
    }
    __syncthreads();
    float u_reg = sh0;

    // ---- main loop ----
    for (int it = 0; it <= NITER; ++it) {
        // ===== row pass =====
        f32x4 tv, rv;
        if (wid == 0 && it > 0) {
            int par_prev = (it - 1) & 1;
            const float* pt = wsf + WSN_T + par_prev * 256 + (lane << 2);
            const float* pr = wsf + WSN_R + par_prev * 256 + (lane << 2);
            asm volatile(
                "global_load_dwordx4 %0, %2, off sc1\n\t"
                "global_load_dwordx4 %1, %3, off sc1"
                : "=&v"(tv), "=&v"(rv) : "v"(pt), "v"(pr) : "memory");
        }
        if (it == 0) {
            f32x4 one = {1.f, 1.f, 1.f, 1.f};
            *(f32x4*)&lv[t << 3] = one;
            *(f32x4*)&lv[(t << 3) + 4] = one;
        } else {
            stage_v8(wsf + WSN_V, t, lv);   // trailing vmcnt(0) also drains tv/rv
        }
        if (wid == 0 && it > 0) {
            asm volatile("" : "+v"(tv), "+v"(rv));
            float gp = tv.x + tv.y + tv.z + tv.w;
            float rm = fmaxf(fmaxf(rv.x, rv.y), fmaxf(rv.z, rv.w));
#pragma unroll
            for (int o = 32; o; o >>= 1) {
                gp += __shfl_xor(gp, o);
                rm = fmaxf(rm, __shfl_xor(rm, o));
            }
            if (lane == 0) { gsh = gp; rsh = rm; }
        }
        __syncthreads();
        float g = (it > 0) ? (mb / (gsh + TINYX)) : 1.f;
        bool last = (it == NITER) || (it >= MIN_IT && rsh < REL_EPS);
        {
            int i = r0 + (wid >> 1);
            const uint2* Kr = (const uint2*)(K + ((size_t)i << 12)) + ((wid & 1) << 9);
            int fbase = (wid & 1) << 11;
            float s = 0.f;
#pragma unroll
            for (int p = 0; p < 8; ++p) {
                int idx = (p << 6) + lane;
                uint2 kk = Kr[idx];
                int f0 = fbase + (idx << 2);
                f32x4 vv = *(const f32x4*)&lv[f0];
                s = fmaf(bfl(kk.x), vv.x, s); s = fmaf(bfh(kk.x), vv.y, s);
                s = fmaf(bfl(kk.y), vv.z, s); s = fmaf(bfh(kk.y), vv.w, s);
            }
            s = wave_sum(s);
            if (lane == 0) red[wid] = s;
        }
        __syncthreads();
        if (t < 4) {
            float y = red[2 * t] + red[2 * t + 1];
            float ue = u_reg * g;
            float rr = ue * y;
            float un = ue * fminf(a_reg / (rr + TINYX), 1.f);
            relu4[t] = fabsf(un - u_reg) / (u_reg + 1e-30f);
            u_reg = un;
            g_store(wsf + WSN_U + r0 + t, u_reg);
        }
        grid_bar(wsu, ++barcnt);

        // ===== col pass =====
        stage_u2(wsf + WSN_U, t, lu);
        __syncthreads();
        float relv = 0.f;
#pragma unroll
        for (int c = 0; c < 2; ++c) {
            int j = j0 + c;
            const uint2* Kc = (const uint2*)(KT + ((size_t)j << 10));
            float s = 0.f;
#pragma unroll
            for (int p = 0; p < 4; ++p) {
                int idx = (p << 6) + lane;
                uint2 kk = Kc[idx];
                int f0 = idx << 2;
                f32x4 uu = *(const f32x4*)&lu[f0];
                s = fmaf(bfl(kk.x), uu.x, s); s = fmaf(bfh(kk.x), uu.y, s);
                s = fmaf(bfl(kk.y), uu.z, s); s = fmaf(bfh(kk.y), uu.w, s);
            }
            s = wave_sum(s);
            if (lane == 0) {
                float vj = (c == 0) ? v_reg0 : v_reg1;
                float cc = vj * s;
                float bj = (c == 0) ? b_reg0 : b_reg1;
                float scv = fminf(bj / (cc + TINYX), 1.f);
                float vn = vj * scv;
                relv = fmaxf(relv, fabsf(vn - vj) / (vj + 1e-30f));
                if (c == 0) v_reg0 = vn; else v_reg1 = vn;
                g_store(wsf + WSN_V + j, vn);
                float cw = cc * scv;
                cws[(wid << 1) + c] = cw;
                if (last) usage[j] = cw;
            }
        }
        if (lane == 0) cwr[wid] = relv;
        __syncthreads();
        if (t == 0) {
            float ts = 0.f;
#pragma unroll
            for (int q = 0; q < 16; ++q) ts += cws[q];
            if (last) {
                atomicAdd(&out[1 + (size_t)MM * NN], ts);   // transported mass
            } else {
                float rl = fmaxf(fmaxf(relu4[0], relu4[1]), fmaxf(relu4[2], relu4[3]));
#pragma unroll
                for (int q = 0; q < 8; ++q) rl = fmaxf(rl, cwr[q]);
                g_store(wsf + WSN_T + (it & 1) * 256 + bid, ts);
                g_store(wsf + WSN_R + (it & 1) * 256 + bid, rl);
            }
        }
        grid_bar(wsu, ++barcnt);
        if (last) break;
    }

    // ---- writeback: plan = K*u*v (own u from regs), score via atomic ----
    if (t < 4) lu4s[t] = u_reg;
    stage_v8(wsf + WSN_V, t, lv);
    __syncthreads();
    float sc = 0.f;
    for (int r = 0; r < 4; ++r) {
        int i = r0 + r;
        float ui = lu4s[r];
        const unsigned* Kr = (const unsigned*)K + ((size_t)i << 11);
        float2* Pr = (float2*)(plan + ((size_t)i << 12));
#pragma unroll
        for (int q = 0; q < 4; ++q) {
            int dw = t + (q << 9);
            unsigned kk = Kr[dw];
            float k0 = bfl(kk), k1 = bfh(kk);
            f32x2 vv = *(const f32x2*)&lv[dw << 1];
            float p0 = k0 * ui * vv.x;
            float p1 = k1 * ui * vv.y;
            Pr[dw] = make_float2(p0, p1);
            sc += p0 * __logf(k0) + p1 * __logf(k1);
        }
    }
    sc = wave_sum(sc);
    if (lane == 0) red[wid] = sc;
    __syncthreads();
    if (t == 0) {
        float st = 0.f;
#pragma unroll
        for (int q = 0; q < 8; ++q) st += red[q];
        atomicAdd(&out[0], EPSX * st);
    }
}

// ======================= f32 fallback (small ws) — round-8 proven =======================
__global__ __launch_bounds__(256) void k_cost(const float* U, const float* V, float* cost,
                                              float* ws, const float* cap, float* out) {
    if (blockIdx.x == 256) {
        int t = threadIdx.x;
        for (int i = t; i < 512; i += 256) ws[i] = 0.f;
        for (int i = 6912 + t; i < 7680; i += 256) ws[i] = 0.f;
        if (t == 0) { out[0] = 0.f; out[1 + (size_t)MM * NN] = 0.f; }
        float m = 0.f;
        for (int j = t; j < NN; j += 256) m = fmaxf(m, cap[j]);
        __shared__ float red[4];
        m = wave_max(m);
        if ((t & 63) == 0) red[t >> 6] = m;
        __syncthreads();
        if (t == 0) ws[WS_MAXCAP] = fmaxf(fmaxf(red[0], red[1]), fmaxf(red[2], red[3]));
        return;
    }
    __shared__ __align__(16) float As[32][132];
    __shared__ __align__(16) float Bs[32][132];
    __shared__ float su2[128], sv2[128];
    __shared__ float red[4];
    int t = threadIdx.x;
    int tr0 = (blockIdx.x >> 5) << 7;
    int tc0 = (blockIdx.x & 31) << 7;
    int tx = t & 15, ty = t >> 4;
    float acc[8][8] = {};
    float na = 0.f, nb = 0.f;
    for (int kk = 0; kk < DD; kk += 32) {
#pragma unroll
        for (int p = 0; p < 4; p++) {
            int s = t + (p << 8);
            int r = s >> 3, kp = (s & 7) << 2;
            float4 av = *(const float4*)(U + (size_t)(tr0 + r) * DD + kk + kp);
            As[kp][r] = av.x; As[kp + 1][r] = av.y; As[kp + 2][r] = av.z; As[kp + 3][r] = av.w;
            float4 bv = *(const float4*)(V + (size_t)(tc0 + r) * DD + kk + kp);
            Bs[kp][r] = bv.x; Bs[kp + 1][r] = bv.y; Bs[kp + 2][r] = bv.z; Bs[kp + 3][r] = bv.w;
        }
        __syncthreads();
        if (t < 128) {
            float s = 0.f;
            for (int k = 0; k < 32; k++) { float x = As[k][t]; s = fmaf(x, x, s); }
            na += s;
        } else {
            int c = t - 128;
            float s = 0.f;
            for (int k = 0; k < 32; k++) { float x = Bs[k][c]; s = fmaf(x, x, s); }
            nb += s;
        }
#pragma unroll 2
        for (int k = 0; k < 32; ++k) {
            f32x4 a0 = *(const f32x4*)&As[k][ty << 3];
            f32x4 a1 = *(const f32x4*)&As[k][(ty << 3) + 4];
            f32x4 b0 = *(const f32x4*)&Bs[k][tx << 3];
            f32x4 b1 = *(const f32x4*)&Bs[k][(tx << 3) + 4];
            float av[8] = {a0.x, a0.y, a0.z, a0.w, a1.x, a1.y, a1.z, a1.w};
            float bv[8] = {b0.x, b0.y, b0.z, b0.w, b1.x, b1.y, b1.z, b1.w};
#pragma unroll
            for (int i = 0; i < 8; i++)
#pragma unroll
                for (int j = 0; j < 8; j++)
                    acc[i][j] = fmaf(av[i], bv[j], acc[i][j]);
        }
        __syncthreads();
    }
    if (t < 128) su2[t] = na;
    else sv2[t - 128] = nb;
    __syncthreads();
    float u2l[8], v2l[8];
#pragma unroll
    for (int i = 0; i < 8; i++) u2l[i] = su2[(ty << 3) + i];
#pragma unroll
    for (int j = 0; j < 8; j++) v2l[j] = sv2[(tx << 3) + j];
    float lmax = 0.f;
#pragma unroll
    for (int i = 0; i < 8; i++) {
        f32x4 c0, c1;
#pragma unroll
        for (int j = 0; j < 4; j++) {
            float c = fmaxf(u2l[i] + v2l[j] - 2.f * acc[i][j], 0.f);
            c0[j] = c; lmax = fmaxf(lmax, c);
        }
#pragma unroll
        for (int j = 4; j < 8; j++) {
            float c = fmaxf(u2l[i] + v2l[j] - 2.f * acc[i][j], 0.f);
            c1[j - 4] = c; lmax = fmaxf(lmax, c);
        }
        size_t rowoff = (size_t)(tr0 + (ty << 3) + i) * NN + tc0 + (tx << 3);
        *(f32x4*)&cost[rowoff] = c0;
        *(f32x4*)&cost[rowoff + 4] = c1;
    }
    lmax = wave_max(lmax);
    if ((t & 63) == 0) red[t >> 6] = lmax;
    __syncthreads();
    if (t == 0)
        ws[WS_CMAX + blockIdx.x] = fmaxf(fmaxf(red[0], red[1]), fmaxf(red[2], red[3]));
}

__global__ void k_makeK_f32(float* costK, const float* cap, float* ws) {
    __shared__ float red[4];
    __shared__ float shmax;
    int t = threadIdx.x;
    {
        float m = 0.f;
        if (t < 64) {
            f32x4 mv = *(const f32x4*)&ws[WS_CMAX + (t << 2)];
            m = fmaxf(fmaxf(mv.x, mv.y), fmaxf(mv.z, mv.w));
        }
        m = wave_max(m);
        if ((t & 63) == 0) red[t >> 6] = m;
        __syncthreads();
        if (t == 0) shmax = fmaxf(fmaxf(red[0], red[1]), fmaxf(red[2], red[3]));
        __syncthreads();
    }
    float inv_mc = 1.f / (shmax + TINYX);
    float inv_cap = 1.f / (ws[WS_MAXCAP] + TINYX);
    float lsum = 0.f;
    for (int s = 0; s < 4; s++) {
        size_t idx = (size_t)blockIdx.x * 1024 + s * 256 + t;
        int gc = (int)(idx & (NN - 1));
        float c = costK[idx] * inv_mc + STRENGTH * (1.f - cap[gc] * inv_cap);
        float kf = expf(-c * (1.f / EPSX));
        costK[idx] = kf;
        lsum += kf;
    }
    lsum = wave_sum(lsum);
    if ((t & 63) == 0) red[t >> 6] = lsum;
    __syncthreads();
    if (t == 0)
        atomicAdd(&ws[WS_KSUM_SLOTS + (blockIdx.x & 63)], red[0] + red[1] + red[2] + red[3]);
}

__global__ void k_init_uv(float* ws, const float* mbp) {
    __shared__ float s0s;
    int t = threadIdx.x;
    if (t < 64) {
        float s = ws[WS_KSUM_SLOTS + t];
        s = wave_sum(s);
        if (t == 0) s0s = mbp[0] / (s + TINYX);
    }
    __syncthreads();
    float s0 = s0s;
    for (int i = t; i < MM; i += 256) ws[WS_U + i] = s0;
    for (int j = t; j < NN; j += 256) ws[WS_V + j] = 1.f;
}

__global__ __launch_bounds__(256) void k_row_f32(const float* K, const float* a, const float* mbp,
                                                 float* ws, int iter) {
    __shared__ float red[4];
    int t = threadIdx.x, i = blockIdx.x;
    const float* Krow = K + (size_t)i * NN;
    const float* v = ws + WS_V;
    float s = 0.f;
    for (int p = 0; p < 16; p++) {
        int j = t + p * 256;
        s += Krow[j] * v[j];
    }
    s = wave_sum(s);
    if ((t & 63) == 0) red[t >> 6] = s;
    __syncthreads();
    if (blockIdx.x == 0 && t >= 64 && t < 128) ws[WS_T_SLOTS + (iter & 1) * 64 + t - 64] = 0.f;
    if (t < 64) {
        float y = red[0] + red[1] + red[2] + red[3];
        float g = 1.f;
        if (iter > 0) {
            float tp = ws[WS_T_SLOTS + ((iter - 1) & 1) * 64 + t];
            tp = wave_sum(tp);
            g = mbp[0] / (tp + TINYX);
        }
        if (t == 0) {
            float ue = ws[WS_U + i] * g;
            float r = ue * y;
            ws[WS_U + i] = ue * fminf(a[i] / (r + TINYX), 1.f);
        }
    }
}

__global__ __launch_bounds__(256) void k_col_f32(const float* K, const float* b, float* ws,
                                                 int iter, float* usage_out) {
    __shared__ float red[4];
    int t = threadIdx.x;
    int j = blockIdx.x * 256 + t;
    const float* u = ws + WS_U;
    float s = 0.f;
    for (int i = 0; i < MM; i++) s += K[(size_t)i * NN + j] * u[i];
    float vj = ws[WS_V + j];
    float c = vj * s;
    float sc = fminf(b[j] / (c + TINYX), 1.f);
    ws[WS_V + j] = vj * sc;
    float cw = c * sc;
    if (usage_out) usage_out[j] = cw;
    float bs = wave_sum(cw);
    if ((t & 63) == 0) red[t >> 6] = bs;
    __syncthreads();
    if (t == 0)
        atomicAdd(&ws[WS_T_SLOTS + (iter & 1) * 64 + (blockIdx.x & 63)],
                  red[0] + red[1] + red[2] + red[3]);
}

__global__ __launch_bounds__(256) void k_write_f32(float* K, float* ws) {
    __shared__ float red[4];
    int t = threadIdx.x;
    float sc = 0.f;
    for (int s = 0; s < 4; s++) {
        size_t idx = (size_t)blockIdx.x * 256 + (size_t)s * 1048576 + t;
        int i = (int)(idx >> 12), j = (int)(idx & (NN - 1));
        float kf = K[idx];
        float p = kf * ws[WS_U + i] * ws[WS_V + j];
        K[idx] = p;
        sc += p * __logf(kf);
    }
    sc = wave_sum(sc);
    if ((t & 63) == 0) red[t >> 6] = sc;
    __syncthreads();
    if (t == 0)
        atomicAdd(&ws[WS_SCORE_SLOTS + (blockIdx.x & 63)], red[0] + red[1] + red[2] + red[3]);
}

__global__ void k_epi(const float* ws, float* out) {
    int t = threadIdx.x;
    float s = ws[WS_SCORE_SLOTS + t];
    s = wave_sum(s);
    float tt = ws[WS_T_SLOTS + (NITER & 1) * 64 + t];
    tt = wave_sum(tt);
    if (t == 0) {
        out[0] = EPSX * s;
        out[1 + (size_t)MM * NN] = tt;
    }
}

extern "C" void kernel_launch(void* const* d_in, const int* in_sizes, int n_in,
                              void* d_out, int out_size, void* d_ws, size_t ws_size,
                              hipStream_t stream) {
    const float* U = (const float*)d_in[0];
    const float* V = (const float*)d_in[1];
    const float* a = (const float*)d_in[2];
    const float* b = (const float*)d_in[3];
    const float* mb = (const float*)d_in[4];
    float* out = (float*)d_out;
    float* ws = (float*)d_ws;
    float* plan = out + 1;
    float* usage = out + 2 + (size_t)MM * NN;

    bool fast = (ws_size >= FAST_NEED);
    ushortT* K = (ushortT*)((char*)d_ws + K_BYTE_OFF);
    ushortT* KT = K + (size_t)MM * NN;

    if (fast) {
        k_zero<<<1, 256, 0, stream>>>(ws, out, b);
        k_costK<<<512, 256, 0, stream>>>(U, V, b, ws, K, KT);
        k_loop<<<NWG, NTHR, 0, stream>>>(K, KT, a, b, mb, ws, out);
    } else {
        k_cost<<<257, 256, 0, stream>>>(U, V, plan, ws, b, out);
        k_makeK_f32<<<4096, 256, 0, stream>>>(plan, b, ws);
        k_init_uv<<<1, 256, 0, stream>>>(ws, mb);
        for (int it = 0; it <= NITER; it++) {
            k_row_f32<<<MM, 256, 0, stream>>>(plan, a, mb, ws, it);
            k_col_f32<<<NN / 256, 256, 0, stream>>>(plan, b, ws, it, (it == NITER) ? usage : nullptr);
        }
        k_write_f32<<<4096, 256, 0, stream>>>(plan, ws);
        k_epi<<<1, 64, 0, stream>>>(ws, out);
    }
}

// Round 19
// 76.360 us; speedup vs baseline: 1.1533x; 1.1533x over previous
//
#include <hip/hip_runtime.h>
#include <hip/hip_bf16.h>
#include <stdint.h>

typedef unsigned short ushortT;
typedef float f32x4 __attribute__((ext_vector_type(4)));
typedef float f32x2 __attribute__((ext_vector_type(2)));
typedef unsigned u32x4 __attribute__((ext_vector_type(4)));
typedef ushortT u16x4 __attribute__((ext_vector_type(4)));
typedef ushortT u16x8 __attribute__((ext_vector_type(8)));

#define MM 1024
#define NN 4096
#define DD 128
#define EPSX 0.05f
#define STRENGTH 0.5f
#define TINYX 1e-12f
#define NITER 50
#define MIN_IT 2
#define REL_EPS 2e-1f

// ---- ws layout (float indices) ----
#define WS_MAXCAP  1
#define WS_KSUM_SLOTS 16   // 64 slots
#define WS_SCORE_SLOTS 80  // 64 slots (fallback)
#define WS_T_SLOTS 144     // 2 x 64 slots (fallback)
#define WS_U 512           // fallback u
#define WS_V 1536          // fallback v
#define WS_CMAX 512        // per-WG cost-max slots (512..1023 used by fast path)
#define K_BYTE_OFF 32768
#define FAST_NEED (32768ull + 2ull * 8388608ull)

// ---- fast-path layout ----
#define WSN_U   1024       // 1024 floats
#define WSN_V   2048       // 4096 floats
#define WSN_T   6144       // 2 x 256 per-WG t slots
#define WSB_FLAGS 6912     // 256 u32 arrival flags
#define WSB_MST 7424       // master release word
#define WSN_R   7680       // 2 x 256 per-WG rel slots
#define NWG 256
#define NTHR 512

__device__ inline float bfl(unsigned u) { return __uint_as_float(u << 16); }
__device__ inline float bfh(unsigned u) { return __uint_as_float(u & 0xffff0000u); }
__device__ inline float bf2f(ushortT u) { return __uint_as_float(((unsigned)u) << 16); }
__device__ inline ushortT f2bf(float f) {
    unsigned b = __float_as_uint(f);
    b += 0x7fffu + ((b >> 16) & 1u);
    return (ushortT)(b >> 16);
}
__device__ inline float wave_sum(float v) {
    for (int o = 32; o; o >>= 1) v += __shfl_down(v, o);
    return v;
}
__device__ inline float wave_max(float v) {
    for (int o = 32; o; o >>= 1) v = fmaxf(v, __shfl_down(v, o));
    return v;
}

__device__ inline void g_store(float* p, float v) {
    __hip_atomic_store(p, v, __ATOMIC_RELAXED, __HIP_MEMORY_SCOPE_AGENT);
}
__device__ inline float g_load(const float* p) {
    return __hip_atomic_load((float*)p, __ATOMIC_RELAXED, __HIP_MEMORY_SCOPE_AGENT);
}
__device__ inline void g_store_u(unsigned* p, unsigned v) {
    __hip_atomic_store(p, v, __ATOMIC_RELAXED, __HIP_MEMORY_SCOPE_AGENT);
}
__device__ inline unsigned g_load_u(const unsigned* p) {
    return __hip_atomic_load((unsigned*)p, __ATOMIC_RELAXED, __HIP_MEMORY_SCOPE_AGENT);
}

__device__ inline void stage_v8(const float* vbase, int t, float* lv) {
    f32x4 x0, x1;
    const float* p0 = vbase + (t << 3);
    const float* p1 = p0 + 4;
    asm volatile(
        "global_load_dwordx4 %0, %2, off sc1\n\t"
        "global_load_dwordx4 %1, %3, off sc1\n\t"
        "s_waitcnt vmcnt(0)"
        : "=&v"(x0), "=&v"(x1) : "v"(p0), "v"(p1) : "memory");
    *(f32x4*)&lv[t << 3] = x0;
    *(f32x4*)&lv[(t << 3) + 4] = x1;
}
__device__ inline void stage_u2(const float* ubase, int t, float* lu) {
    f32x2 x0;
    const float* p0 = ubase + (t << 1);
    asm volatile(
        "global_load_dwordx2 %0, %1, off sc1\n\t"
        "s_waitcnt vmcnt(0)"
        : "=&v"(x0) : "v"(p0) : "memory");
    *(f32x2*)&lu[t << 1] = x0;
}

// Zero-contention flag grid barrier (monotonic rounds, sc1 only, no fences).
// Works under a PLAIN launch: grid = 256 <= 256 CUs with __launch_bounds__(512,1)
// guarantees all WGs co-resident (proven rounds 15-18). Every wave drains its OWN
// vmem ops first (per-wave vmcnt covers inline-asm sc1 stores).
__device__ inline void grid_bar(unsigned* w, unsigned round) {
    asm volatile("s_waitcnt vmcnt(0)" ::: "memory");
    __syncthreads();
    if (blockIdx.x == 0) {
        if (threadIdx.x < 64) {
            if (threadIdx.x == 0) g_store_u(&w[WSB_FLAGS], round);
            const unsigned* fp = &w[WSB_FLAGS + (threadIdx.x << 2)];
            for (;;) {
                u32x4 f;
                asm volatile("global_load_dwordx4 %0, %1, off sc1\n\ts_waitcnt vmcnt(0)"
                             : "=&v"(f) : "v"(fp) : "memory");
                unsigned mn = f.x < f.y ? f.x : f.y;
                unsigned mz = f.z < f.w ? f.z : f.w;
                mn = mn < mz ? mn : mz;
#pragma unroll
                for (int o = 32; o; o >>= 1) {
                    unsigned ot = (unsigned)__shfl_xor((int)mn, o);
                    mn = mn < ot ? mn : ot;
                }
                if (mn >= round) break;
            }
            if (threadIdx.x == 0) g_store_u(&w[WSB_MST], round);
        }
    } else {
        if (threadIdx.x == 0) {
            g_store_u(&w[WSB_FLAGS + blockIdx.x], round);
            while (g_load_u(&w[WSB_MST]) < round) {}
            asm volatile("" ::: "memory");
        }
    }
    __syncthreads();
}

// ------- fast-path cost GEMM: 64x128 tiles (513 WGs -> 2 WGs/CU), bf16 out -------
// block 512 = init (zero scalars/ksum/flags/out accumulators, maxcap)
__global__ __launch_bounds__(256) void k_costb(const float* U, const float* V, ushortT* costb,
                                               float* ws, const float* cap, float* out) {
    if (blockIdx.x == 512) {
        int t = threadIdx.x;
        for (int i = t; i < 512; i += 256) ws[i] = 0.f;          // scalars + ksum slots
        for (int i = 6912 + t; i < 7680; i += 256) ws[i] = 0.f;  // flags + master
        if (t == 0) { out[0] = 0.f; out[1 + (size_t)MM * NN] = 0.f; }
        float m = 0.f;
        for (int j = t; j < NN; j += 256) m = fmaxf(m, cap[j]);
        __shared__ float red[4];
        m = wave_max(m);
        if ((t & 63) == 0) red[t >> 6] = m;
        __syncthreads();
        if (t == 0) ws[WS_MAXCAP] = fmaxf(fmaxf(red[0], red[1]), fmaxf(red[2], red[3]));
        return;
    }
    __shared__ __align__(16) float As[32][68];    // [k][row 0..63]
    __shared__ __align__(16) float Bs[32][132];   // [k][col 0..127]
    __shared__ float su2[64], sv2[128];
    __shared__ float red[4];
    int t = threadIdx.x;
    int tr0 = (blockIdx.x >> 5) << 6;   // 16 row tiles (64 rows)
    int tc0 = (blockIdx.x & 31) << 7;   // 32 col tiles (128 cols)
    int tx = t & 15, ty = t >> 4;       // 8 cols x 4 rows per thread
    float acc[4][8] = {};
    float na = 0.f, nb = 0.f;
    float4 pa[2], pb[4];
#pragma unroll
    for (int p = 0; p < 2; p++) {
        int f = t + (p << 8);
        int r = f >> 3, kp = (f & 7) << 2;
        pa[p] = *(const float4*)(U + (size_t)(tr0 + r) * DD + kp);
    }
#pragma unroll
    for (int p = 0; p < 4; p++) {
        int f = t + (p << 8);
        int r = f >> 3, kp = (f & 7) << 2;
        pb[p] = *(const float4*)(V + (size_t)(tc0 + r) * DD + kp);
    }
    for (int kk = 0; kk < DD; kk += 32) {
#pragma unroll
        for (int p = 0; p < 2; p++) {
            int f = t + (p << 8);
            int r = f >> 3, kp = (f & 7) << 2;
            As[kp][r] = pa[p].x; As[kp + 1][r] = pa[p].y;
            As[kp + 2][r] = pa[p].z; As[kp + 3][r] = pa[p].w;
        }
#pragma unroll
        for (int p = 0; p < 4; p++) {
            int f = t + (p << 8);
            int r = f >> 3, kp = (f & 7) << 2;
            Bs[kp][r] = pb[p].x; Bs[kp + 1][r] = pb[p].y;
            Bs[kp + 2][r] = pb[p].z; Bs[kp + 3][r] = pb[p].w;
        }
        __syncthreads();
        if (kk + 32 < DD) {
#pragma unroll
            for (int p = 0; p < 2; p++) {
                int f = t + (p << 8);
                int r = f >> 3, kp = (f & 7) << 2;
                pa[p] = *(const float4*)(U + (size_t)(tr0 + r) * DD + kk + 32 + kp);
            }
#pragma unroll
            for (int p = 0; p < 4; p++) {
                int f = t + (p << 8);
                int r = f >> 3, kp = (f & 7) << 2;
                pb[p] = *(const float4*)(V + (size_t)(tc0 + r) * DD + kk + 32 + kp);
            }
        }
        if (t < 64) {
            float s = 0.f;
            for (int k = 0; k < 32; k++) { float x = As[k][t]; s = fmaf(x, x, s); }
            na += s;
        } else if (t < 192) {
            int c = t - 64;
            float s = 0.f;
            for (int k = 0; k < 32; k++) { float x = Bs[k][c]; s = fmaf(x, x, s); }
            nb += s;
        }
#pragma unroll 2
        for (int k = 0; k < 32; ++k) {
            f32x4 a0 = *(const f32x4*)&As[k][ty << 2];
            f32x4 b0 = *(const f32x4*)&Bs[k][tx << 3];
            f32x4 b1 = *(const f32x4*)&Bs[k][(tx << 3) + 4];
            float av[4] = {a0.x, a0.y, a0.z, a0.w};
            float bv[8] = {b0.x, b0.y, b0.z, b0.w, b1.x, b1.y, b1.z, b1.w};
#pragma unroll
            for (int i = 0; i < 4; i++)
#pragma unroll
                for (int j = 0; j < 8; j++)
                    acc[i][j] = fmaf(av[i], bv[j], acc[i][j]);
        }
        __syncthreads();
    }
    if (t < 64) su2[t] = na;
    else if (t < 192) sv2[t - 64] = nb;
    __syncthreads();
    float u2l[4], v2l[8];
#pragma unroll
    for (int i = 0; i < 4; i++) u2l[i] = su2[(ty << 2) + i];
#pragma unroll
    for (int j = 0; j < 8; j++) v2l[j] = sv2[(tx << 3) + j];
    float lmax = 0.f;
#pragma unroll
    for (int i = 0; i < 4; i++) {
        u16x8 cb;
#pragma unroll
        for (int j = 0; j < 8; j++) {
            float c = fmaxf(u2l[i] + v2l[j] - 2.f * acc[i][j], 0.f);
            lmax = fmaxf(lmax, c);
            cb[j] = f2bf(c);
        }
        *(u16x8*)&costb[(size_t)(tr0 + (ty << 2) + i) * NN + tc0 + (tx << 3)] = cb;
    }
    lmax = wave_max(lmax);
    if ((t & 63) == 0) red[t >> 6] = lmax;
    __syncthreads();
    if (t == 0)
        ws[WS_CMAX + blockIdx.x] = fmaxf(fmaxf(red[0], red[1]), fmaxf(red[2], red[3]));
}

// ---------------- make K (bf16) + K^T + Ksum (reads bf16 cost) ----------------
__global__ __launch_bounds__(256) void k_makeK(const ushortT* costb, const float* cap, float* ws,
                                               ushortT* K, ushortT* KT) {
    __shared__ __align__(8) ushortT tile[64][66];
    __shared__ float red[4];
    __shared__ float shmax;
    int t = threadIdx.x;
    {
        float m = 0.f;
        if (t < 128) {
            f32x4 mv = *(const f32x4*)&ws[WS_CMAX + (t << 2)];
            m = fmaxf(fmaxf(mv.x, mv.y), fmaxf(mv.z, mv.w));
        }
        m = wave_max(m);
        if ((t & 63) == 0) red[t >> 6] = m;
        __syncthreads();
        if (t == 0) shmax = fmaxf(red[0], red[1]);
        __syncthreads();
    }
    int tr0 = (blockIdx.x >> 6) << 6, tc0 = (blockIdx.x & 63) << 6;
    float inv_mc = 1.f / (shmax + TINYX);
    float inv_cap = 1.f / (ws[WS_MAXCAP] + TINYX);
    float lsum = 0.f;
#pragma unroll
    for (int s = 0; s < 4; s++) {
        int lr = s * 16 + (t >> 4), lc = (t & 15) << 2;
        int gr = tr0 + lr, gc = tc0 + lc;
        u16x4 cv = *(const u16x4*)&costb[(size_t)gr * NN + gc];
        f32x4 capv = *(const f32x4*)&cap[gc];
        u16x4 kb;
#pragma unroll
        for (int i = 0; i < 4; i++) {
            float c = bf2f(cv[i]) * inv_mc + STRENGTH * (1.f - capv[i] * inv_cap);
            float kf = expf(-c * (1.f / EPSX));
            lsum += kf;
            kb[i] = f2bf(kf);
        }
        *(u16x4*)&K[(size_t)gr * NN + gc] = kb;
        *(u16x4*)&tile[lr][lc] = kb;
    }
    __syncthreads();
#pragma unroll
    for (int s = 0; s < 4; s++) {
        int lr = s * 16 + (t >> 4), lc = (t & 15) << 2;
        u16x4 kb;
#pragma unroll
        for (int i = 0; i < 4; i++) kb[i] = tile[lc + i][lr];
        *(u16x4*)&KT[(size_t)(tc0 + lr) * MM + tr0 + lc] = kb;
    }
    lsum = wave_sum(lsum);
    if ((t & 63) == 0) red[t >> 6] = lsum;
    __syncthreads();
    if (t == 0)
        atomicAdd(&ws[WS_KSUM_SLOTS + (blockIdx.x & 63)], red[0] + red[1] + red[2] + red[3]);
}

// ============ persistent loop kernel (PLAIN launch; 256 WGs co-resident) ============
__global__ __launch_bounds__(NTHR, 1) void k_loop(const ushortT* __restrict__ K,
                                                  const ushortT* __restrict__ KT,
                                                  const float* __restrict__ a,
                                                  const float* __restrict__ b,
                                                  const float* __restrict__ mbp,
                                                  float* __restrict__ wsf,
                                                  float* __restrict__ out) {
    __shared__ __align__(16) float lv[4096];
    __shared__ __align__(16) float lu[1024];
    __shared__ float red[8];
    __shared__ float cws[16];
    __shared__ float cwr[8];
    __shared__ float relu4[4];
    __shared__ float lu4s[4];
    __shared__ float gsh;
    __shared__ float rsh;
    __shared__ float sh0;

    int t = threadIdx.x, lane = t & 63, wid = t >> 6;
    int bid = blockIdx.x;
    unsigned* wsu = (unsigned*)wsf;
    float mb = mbp[0];
    float* plan = out + 1;
    float* usage = out + 2 + (size_t)MM * NN;
    int r0 = bid << 2;
    int j0 = (bid << 4) + (wid << 1);
    unsigned barcnt = 0;

    float a_reg = (t < 4) ? a[r0 + t] : 0.f;
    float b_reg0 = 0.f, b_reg1 = 0.f;
    if (lane == 0) { b_reg0 = b[j0]; b_reg1 = b[j0 + 1]; }
    float v_reg0 = 1.f, v_reg1 = 1.f;

    // ---- phase 0 (local only, no barrier): u = mb/Ksum ----
    if (wid == 0) {
        float s = g_load(wsf + WS_KSUM_SLOTS + lane);
        s = wave_sum(s);
        if (lane == 0) sh0 = mb / (s + TINYX);
    }
    __syncthreads();
    float u_reg = sh0;

    // ---- main loop ----
    for (int it = 0; it <= NITER; ++it) {
        // ===== row pass =====
        f32x4 tv, rv;
        if (wid == 0 && it > 0) {
            int par_prev = (it - 1) & 1;
            const float* pt = wsf + WSN_T + par_prev * 256 + (lane << 2);
            const float* pr = wsf + WSN_R + par_prev * 256 + (lane << 2);
            asm volatile(
                "global_load_dwordx4 %0, %2, off sc1\n\t"
                "global_load_dwordx4 %1, %3, off sc1"
                : "=&v"(tv), "=&v"(rv) : "v"(pt), "v"(pr) : "memory");
        }
        if (it == 0) {
            f32x4 one = {1.f, 1.f, 1.f, 1.f};
            *(f32x4*)&lv[t << 3] = one;
            *(f32x4*)&lv[(t << 3) + 4] = one;
        } else {
            stage_v8(wsf + WSN_V, t, lv);   // trailing vmcnt(0) also drains tv/rv
        }
        if (wid == 0 && it > 0) {
            asm volatile("" : "+v"(tv), "+v"(rv));
            float gp = tv.x + tv.y + tv.z + tv.w;
            float rm = fmaxf(fmaxf(rv.x, rv.y), fmaxf(rv.z, rv.w));
#pragma unroll
            for (int o = 32; o; o >>= 1) {
                gp += __shfl_xor(gp, o);
                rm = fmaxf(rm, __shfl_xor(rm, o));
            }
            if (lane == 0) { gsh = gp; rsh = rm; }
        }
        __syncthreads();
        float g = (it > 0) ? (mb / (gsh + TINYX)) : 1.f;
        bool last = (it == NITER) || (it >= MIN_IT && rsh < REL_EPS);
        {
            int i = r0 + (wid >> 1);
            const uint2* Kr = (const uint2*)(K + ((size_t)i << 12)) + ((wid & 1) << 9);
            int fbase = (wid & 1) << 11;
            float s = 0.f;
#pragma unroll
            for (int p = 0; p < 8; ++p) {
                int idx = (p << 6) + lane;
                uint2 kk = Kr[idx];
                int f0 = fbase + (idx << 2);
                f32x4 vv = *(const f32x4*)&lv[f0];
                s = fmaf(bfl(kk.x), vv.x, s); s = fmaf(bfh(kk.x), vv.y, s);
                s = fmaf(bfl(kk.y), vv.z, s); s = fmaf(bfh(kk.y), vv.w, s);
            }
            s = wave_sum(s);
            if (lane == 0) red[wid] = s;
        }
        __syncthreads();
        if (t < 4) {
            float y = red[2 * t] + red[2 * t + 1];
            float ue = u_reg * g;
            float rr = ue * y;
            float un = ue * fminf(a_reg / (rr + TINYX), 1.f);
            relu4[t] = fabsf(un - u_reg) / (u_reg + 1e-30f);
            u_reg = un;
            g_store(wsf + WSN_U + r0 + t, u_reg);
        }
        grid_bar(wsu, ++barcnt);

        // ===== col pass =====
        stage_u2(wsf + WSN_U, t, lu);
        __syncthreads();
        float relv = 0.f;
#pragma unroll
        for (int c = 0; c < 2; ++c) {
            int j = j0 + c;
            const uint2* Kc = (const uint2*)(KT + ((size_t)j << 10));
            float s = 0.f;
#pragma unroll
            for (int p = 0; p < 4; ++p) {
                int idx = (p << 6) + lane;
                uint2 kk = Kc[idx];
                int f0 = idx << 2;
                f32x4 uu = *(const f32x4*)&lu[f0];
                s = fmaf(bfl(kk.x), uu.x, s); s = fmaf(bfh(kk.x), uu.y, s);
                s = fmaf(bfl(kk.y), uu.z, s); s = fmaf(bfh(kk.y), uu.w, s);
            }
            s = wave_sum(s);
            if (lane == 0) {
                float vj = (c == 0) ? v_reg0 : v_reg1;
                float cc = vj * s;
                float bj = (c == 0) ? b_reg0 : b_reg1;
                float scv = fminf(bj / (cc + TINYX), 1.f);
                float vn = vj * scv;
                relv = fmaxf(relv, fabsf(vn - vj) / (vj + 1e-30f));
                if (c == 0) v_reg0 = vn; else v_reg1 = vn;
                g_store(wsf + WSN_V + j, vn);
                float cw = cc * scv;
                cws[(wid << 1) + c] = cw;
                if (last) usage[j] = cw;
            }
        }
        if (lane == 0) cwr[wid] = relv;
        __syncthreads();
        if (t == 0) {
            float ts = 0.f;
#pragma unroll
            for (int q = 0; q < 16; ++q) ts += cws[q];
            if (last) {
                atomicAdd(&out[1 + (size_t)MM * NN], ts);   // transported mass
            } else {
                float rl = fmaxf(fmaxf(relu4[0], relu4[1]), fmaxf(relu4[2], relu4[3]));
#pragma unroll
                for (int q = 0; q < 8; ++q) rl = fmaxf(rl, cwr[q]);
                g_store(wsf + WSN_T + (it & 1) * 256 + bid, ts);
                g_store(wsf + WSN_R + (it & 1) * 256 + bid, rl);
            }
        }
        grid_bar(wsu, ++barcnt);
        if (last) break;
    }

    // ---- writeback: plan = K*u*v (own u from regs), score via atomic ----
    if (t < 4) lu4s[t] = u_reg;
    stage_v8(wsf + WSN_V, t, lv);
    __syncthreads();
    float sc = 0.f;
    for (int r = 0; r < 4; ++r) {
        int i = r0 + r;
        float ui = lu4s[r];
        const unsigned* Kr = (const unsigned*)K + ((size_t)i << 11);
        float2* Pr = (float2*)(plan + ((size_t)i << 12));
#pragma unroll
        for (int q = 0; q < 4; ++q) {
            int dw = t + (q << 9);
            unsigned kk = Kr[dw];
            float k0 = bfl(kk), k1 = bfh(kk);
            f32x2 vv = *(const f32x2*)&lv[dw << 1];
            float p0 = k0 * ui * vv.x;
            float p1 = k1 * ui * vv.y;
            Pr[dw] = make_float2(p0, p1);
            sc += p0 * __logf(k0) + p1 * __logf(k1);
        }
    }
    sc = wave_sum(sc);
    if (lane == 0) red[wid] = sc;
    __syncthreads();
    if (t == 0) {
        float st = 0.f;
#pragma unroll
        for (int q = 0; q < 8; ++q) st += red[q];
        atomicAdd(&out[0], EPSX * st);
    }
}

// ======================= f32 fallback (small ws) — round-8 proven =======================
__global__ __launch_bounds__(256) void k_cost(const float* U, const float* V, float* cost,
                                              float* ws, const float* cap, float* out) {
    if (blockIdx.x == 256) {
        int t = threadIdx.x;
        for (int i = t; i < 512; i += 256) ws[i] = 0.f;
        for (int i = 6912 + t; i < 7680; i += 256) ws[i] = 0.f;
        if (t == 0) { out[0] = 0.f; out[1 + (size_t)MM * NN] = 0.f; }
        float m = 0.f;
        for (int j = t; j < NN; j += 256) m = fmaxf(m, cap[j]);
        __shared__ float red[4];
        m = wave_max(m);
        if ((t & 63) == 0) red[t >> 6] = m;
        __syncthreads();
        if (t == 0) ws[WS_MAXCAP] = fmaxf(fmaxf(red[0], red[1]), fmaxf(red[2], red[3]));
        return;
    }
    __shared__ __align__(16) float As[32][132];
    __shared__ __align__(16) float Bs[32][132];
    __shared__ float su2[128], sv2[128];
    __shared__ float red[4];
    int t = threadIdx.x;
    int tr0 = (blockIdx.x >> 5) << 7;
    int tc0 = (blockIdx.x & 31) << 7;
    int tx = t & 15, ty = t >> 4;
    float acc[8][8] = {};
    float na = 0.f, nb = 0.f;
    for (int kk = 0; kk < DD; kk += 32) {
#pragma unroll
        for (int p = 0; p < 4; p++) {
            int s = t + (p << 8);
            int r = s >> 3, kp = (s & 7) << 2;
            float4 av = *(const float4*)(U + (size_t)(tr0 + r) * DD + kk + kp);
            As[kp][r] = av.x; As[kp + 1][r] = av.y; As[kp + 2][r] = av.z; As[kp + 3][r] = av.w;
            float4 bv = *(const float4*)(V + (size_t)(tc0 + r) * DD + kk + kp);
            Bs[kp][r] = bv.x; Bs[kp + 1][r] = bv.y; Bs[kp + 2][r] = bv.z; Bs[kp + 3][r] = bv.w;
        }
        __syncthreads();
        if (t < 128) {
            float s = 0.f;
            for (int k = 0; k < 32; k++) { float x = As[k][t]; s = fmaf(x, x, s); }
            na += s;
        } else {
            int c = t - 128;
            float s = 0.f;
            for (int k = 0; k < 32; k++) { float x = Bs[k][c]; s = fmaf(x, x, s); }
            nb += s;
        }
#pragma unroll 2
        for (int k = 0; k < 32; ++k) {
            f32x4 a0 = *(const f32x4*)&As[k][ty << 3];
            f32x4 a1 = *(const f32x4*)&As[k][(ty << 3) + 4];
            f32x4 b0 = *(const f32x4*)&Bs[k][tx << 3];
            f32x4 b1 = *(const f32x4*)&Bs[k][(tx << 3) + 4];
            float av[8] = {a0.x, a0.y, a0.z, a0.w, a1.x, a1.y, a1.z, a1.w};
            float bv[8] = {b0.x, b0.y, b0.z, b0.w, b1.x, b1.y, b1.z, b1.w};
#pragma unroll
            for (int i = 0; i < 8; i++)
#pragma unroll
                for (int j = 0; j < 8; j++)
                    acc[i][j] = fmaf(av[i], bv[j], acc[i][j]);
        }
        __syncthreads();
    }
    if (t < 128) su2[t] = na;
    else sv2[t - 128] = nb;
    __syncthreads();
    float u2l[8], v2l[8];
#pragma unroll
    for (int i = 0; i < 8; i++) u2l[i] = su2[(ty << 3) + i];
#pragma unroll
    for (int j = 0; j < 8; j++) v2l[j] = sv2[(tx << 3) + j];
    float lmax = 0.f;
#pragma unroll
    for (int i = 0; i < 8; i++) {
        f32x4 c0, c1;
#pragma unroll
        for (int j = 0; j < 4; j++) {
            float c = fmaxf(u2l[i] + v2l[j] - 2.f * acc[i][j], 0.f);
            c0[j] = c; lmax = fmaxf(lmax, c);
        }
#pragma unroll
        for (int j = 4; j < 8; j++) {
            float c = fmaxf(u2l[i] + v2l[j] - 2.f * acc[i][j], 0.f);
            c1[j - 4] = c; lmax = fmaxf(lmax, c);
        }
        size_t rowoff = (size_t)(tr0 + (ty << 3) + i) * NN + tc0 + (tx << 3);
        *(f32x4*)&cost[rowoff] = c0;
        *(f32x4*)&cost[rowoff + 4] = c1;
    }
    lmax = wave_max(lmax);
    if ((t & 63) == 0) red[t >> 6] = lmax;
    __syncthreads();
    if (t == 0)
        ws[WS_CMAX + blockIdx.x] = fmaxf(fmaxf(red[0], red[1]), fmaxf(red[2], red[3]));
}

__global__ void k_makeK_f32(float* costK, const float* cap, float* ws) {
    __shared__ float red[4];
    __shared__ float shmax;
    int t = threadIdx.x;
    {
        float m = 0.f;
        if (t < 64) {
            f32x4 mv = *(const f32x4*)&ws[WS_CMAX + (t << 2)];
            m = fmaxf(fmaxf(mv.x, mv.y), fmaxf(mv.z, mv.w));
        }
        m = wave_max(m);
        if ((t & 63) == 0) red[t >> 6] = m;
        __syncthreads();
        if (t == 0) shmax = fmaxf(fmaxf(red[0], red[1]), fmaxf(red[2], red[3]));
        __syncthreads();
    }
    float inv_mc = 1.f / (shmax + TINYX);
    float inv_cap = 1.f / (ws[WS_MAXCAP] + TINYX);
    float lsum = 0.f;
    for (int s = 0; s < 4; s++) {
        size_t idx = (size_t)blockIdx.x * 1024 + s * 256 + t;
        int gc = (int)(idx & (NN - 1));
        float c = costK[idx] * inv_mc + STRENGTH * (1.f - cap[gc] * inv_cap);
        float kf = expf(-c * (1.f / EPSX));
        costK[idx] = kf;
        lsum += kf;
    }
    lsum = wave_sum(lsum);
    if ((t & 63) == 0) red[t >> 6] = lsum;
    __syncthreads();
    if (t == 0)
        atomicAdd(&ws[WS_KSUM_SLOTS + (blockIdx.x & 63)], red[0] + red[1] + red[2] + red[3]);
}

__global__ void k_init_uv(float* ws, const float* mbp) {
    __shared__ float s0s;
    int t = threadIdx.x;
    if (t < 64) {
        float s = ws[WS_KSUM_SLOTS + t];
        s = wave_sum(s);
        if (t == 0) s0s = mbp[0] / (s + TINYX);
    }
    __syncthreads();
    float s0 = s0s;
    for (int i = t; i < MM; i += 256) ws[WS_U + i] = s0;
    for (int j = t; j < NN; j += 256) ws[WS_V + j] = 1.f;
}

__global__ __launch_bounds__(256) void k_row_f32(const float* K, const float* a, const float* mbp,
                                                 float* ws, int iter) {
    __shared__ float red[4];
    int t = threadIdx.x, i = blockIdx.x;
    const float* Krow = K + (size_t)i * NN;
    const float* v = ws + WS_V;
    float s = 0.f;
    for (int p = 0; p < 16; p++) {
        int j = t + p * 256;
        s += Krow[j] * v[j];
    }
    s = wave_sum(s);
    if ((t & 63) == 0) red[t >> 6] = s;
    __syncthreads();
    if (blockIdx.x == 0 && t >= 64 && t < 128) ws[WS_T_SLOTS + (iter & 1) * 64 + t - 64] = 0.f;
    if (t < 64) {
        float y = red[0] + red[1] + red[2] + red[3];
        float g = 1.f;
        if (iter > 0) {
            float tp = ws[WS_T_SLOTS + ((iter - 1) & 1) * 64 + t];
            tp = wave_sum(tp);
            g = mbp[0] / (tp + TINYX);
        }
        if (t == 0) {
            float ue = ws[WS_U + i] * g;
            float r = ue * y;
            ws[WS_U + i] = ue * fminf(a[i] / (r + TINYX), 1.f);
        }
    }
}

__global__ __launch_bounds__(256) void k_col_f32(const float* K, const float* b, float* ws,
                                                 int iter, float* usage_out) {
    __shared__ float red[4];
    int t = threadIdx.x;
    int j = blockIdx.x * 256 + t;
    const float* u = ws + WS_U;
    float s = 0.f;
    for (int i = 0; i < MM; i++) s += K[(size_t)i * NN + j] * u[i];
    float vj = ws[WS_V + j];
    float c = vj * s;
    float sc = fminf(b[j] / (c + TINYX), 1.f);
    ws[WS_V + j] = vj * sc;
    float cw = c * sc;
    if (usage_out) usage_out[j] = cw;
    float bs = wave_sum(cw);
    if ((t & 63) == 0) red[t >> 6] = bs;
    __syncthreads();
    if (t == 0)
        atomicAdd(&ws[WS_T_SLOTS + (iter & 1) * 64 + (blockIdx.x & 63)],
                  red[0] + red[1] + red[2] + red[3]);
}

__global__ __launch_bounds__(256) void k_write_f32(float* K, float* ws) {
    __shared__ float red[4];
    int t = threadIdx.x;
    float sc = 0.f;
    for (int s = 0; s < 4; s++) {
        size_t idx = (size_t)blockIdx.x * 256 + (size_t)s * 1048576 + t;
        int i = (int)(idx >> 12), j = (int)(idx & (NN - 1));
        float kf = K[idx];
        float p = kf * ws[WS_U + i] * ws[WS_V + j];
        K[idx] = p;
        sc += p * __logf(kf);
    }
    sc = wave_sum(sc);
    if ((t & 63) == 0) red[t >> 6] = sc;
    __syncthreads();
    if (t == 0)
        atomicAdd(&ws[WS_SCORE_SLOTS + (blockIdx.x & 63)], red[0] + red[1] + red[2] + red[3]);
}

__global__ void k_epi(const float* ws, float* out) {
    int t = threadIdx.x;
    float s = ws[WS_SCORE_SLOTS + t];
    s = wave_sum(s);
    float tt = ws[WS_T_SLOTS + (NITER & 1) * 64 + t];
    tt = wave_sum(tt);
    if (t == 0) {
        out[0] = EPSX * s;
        out[1 + (size_t)MM * NN] = tt;
    }
}

extern "C" void kernel_launch(void* const* d_in, const int* in_sizes, int n_in,
                              void* d_out, int out_size, void* d_ws, size_t ws_size,
                              hipStream_t stream) {
    const float* U = (const float*)d_in[0];
    const float* V = (const float*)d_in[1];
    const float* a = (const float*)d_in[2];
    const float* b = (const float*)d_in[3];
    const float* mb = (const float*)d_in[4];
    float* out = (float*)d_out;
    float* ws = (float*)d_ws;
    float* plan = out + 1;
    float* usage = out + 2 + (size_t)MM * NN;

    bool fast = (ws_size >= FAST_NEED);
    ushortT* K = (ushortT*)((char*)d_ws + K_BYTE_OFF);
    ushortT* KT = K + (size_t)MM * NN;

    if (fast) {
        ushortT* costb = (ushortT*)plan;   // bf16 cost staged in plan region
        k_costb<<<513, 256, 0, stream>>>(U, V, costb, ws, b, out);
        k_makeK<<<1024, 256, 0, stream>>>(costb, b, ws, K, KT);
        k_loop<<<NWG, NTHR, 0, stream>>>(K, KT, a, b, mb, ws, out);
    } else {
        k_cost<<<257, 256, 0, stream>>>(U, V, plan, ws, b, out);
        k_makeK_f32<<<4096, 256, 0, stream>>>(plan, b, ws);
        k_init_uv<<<1, 256, 0, stream>>>(ws, mb);
        for (int it = 0; it <= NITER; it++) {
            k_row_f32<<<MM, 256, 0, stream>>>(plan, a, mb, ws, it);
            k_col_f32<<<NN / 256, 256, 0, stream>>>(plan, b, ws, it, (it == NITER) ? usage : nullptr);
        }
        k_write_f32<<<4096, 256, 0, stream>>>(plan, ws);
        k_epi<<<1, 64, 0, stream>>>(ws, out);
    }
}